// Round 1
// baseline (53.418 us; speedup 1.0000x reference)
//
#include <hip/hip_runtime.h>
#include <stdint.h>

#define INPUT_SCALE 0.0078125f   // 2^-7

__device__ __forceinline__ uint32_t sadu8(uint32_t a, uint32_t b, uint32_t c) {
#if __has_builtin(__builtin_amdgcn_sad_u8)
    return __builtin_amdgcn_sad_u8(a, b, c);
#else
    uint32_t d;
    asm("v_sad_u8 %0, %1, %2, %3" : "=v"(d) : "v"(a), "v"(b), "v"(c));
    return d;
#endif
}

__device__ __forceinline__ uint32_t qbyte(float x) {
    // round(clip(x*128, -127, 127)) + 128  (rintf = round-half-even, matches jnp.round)
    float v = fminf(fmaxf(x * 128.0f, -127.0f), 127.0f);
    return (uint32_t)((int)rintf(v) + 128);
}

// ---------------- Kernel A: weight scale + quantize + pack ----------------
// qwp layout: u = (f*9 + kpos)*8 + cg ; byte b of u32 = channel 4*cg+b, kpos = kh*3+kw
__global__ __launch_bounds__(256) void quant_weight(const float* __restrict__ w,
                                                    uint32_t* __restrict__ qwp) {
    __shared__ float red[256];
    __shared__ float s_inv;
    int tid = threadIdx.x;
    float m = 0.0f;
    for (int i = tid; i < 9216; i += 256) m = fmaxf(m, fabsf(w[i]));
    red[tid] = m;
    __syncthreads();
    for (int s = 128; s > 0; s >>= 1) {
        if (tid < s) red[tid] = fmaxf(red[tid], red[tid + s]);
        __syncthreads();
    }
    if (tid == 0) {
        float s = fmaxf(red[0] / 127.0f, 1e-8f);
        int e; float fr = frexpf(s, &e);            // s = fr * 2^e, fr in [0.5,1)
        int k = (fr >= 0.70710678118654752f) ? e : e - 1;  // round(log2(s))
        s_inv = exp2f((float)(-k));                 // 1/s_w, exact power of 2
    }
    __syncthreads();
    float inv = s_inv;
    for (int u = tid; u < 2304; u += 256) {
        int f = u / 72, rem = u % 72, kpos = rem / 8, cg = rem % 8;
        int kh = kpos / 3, kw = kpos % 3;
        uint32_t pk = 0;
        #pragma unroll
        for (int b = 0; b < 4; ++b) {
            int c = cg * 4 + b;
            float v = w[((f * 32 + c) * 3 + kh) * 3 + kw] * inv;
            v = fminf(fmaxf(v, -127.0f), 127.0f);
            pk |= ((uint32_t)((int)rintf(v) + 128) & 0xFFu) << (8 * b);
        }
        qwp[u] = pk;
    }
}

// ---------------- Kernel B: quantize + pack x to NHWC bytes ----------------
// qxp: pixel p = n*16384 + h*128 + w ; 32 bytes per pixel = channels 0..31 (bias +128)
__global__ __launch_bounds__(256) void quant_pack_x(const float4* __restrict__ x4,
                                                    uint4* __restrict__ qxp4) {
    int t = blockIdx.x * blockDim.x + threadIdx.x;  // 65536 threads, 4 pixels each
    int p0 = t << 2;
    int n = p0 >> 14;
    int hw = p0 & 16383;
    uint32_t pk[4][8];
    #pragma unroll
    for (int pix = 0; pix < 4; ++pix)
        #pragma unroll
        for (int cg = 0; cg < 8; ++cg) pk[pix][cg] = 0u;
    #pragma unroll
    for (int c = 0; c < 32; ++c) {
        float4 v = x4[(size_t)(n * 32 + c) * 4096 + (hw >> 2)];
        int cg = c >> 2, sh = (c & 3) << 3;
        pk[0][cg] |= qbyte(v.x) << sh;
        pk[1][cg] |= qbyte(v.y) << sh;
        pk[2][cg] |= qbyte(v.z) << sh;
        pk[3][cg] |= qbyte(v.w) << sh;
    }
    #pragma unroll
    for (int pix = 0; pix < 4; ++pix) {
        qxp4[(size_t)(p0 + pix) * 2 + 0] = make_uint4(pk[pix][0], pk[pix][1], pk[pix][2], pk[pix][3]);
        qxp4[(size_t)(p0 + pix) * 2 + 1] = make_uint4(pk[pix][4], pk[pix][5], pk[pix][6], pk[pix][7]);
    }
}

// ---------------- Kernel C: SAD conv via v_sad_u8 ----------------
// Block: 32 (w) x 16 (h) tile of one image. 256 threads: lane owns 2 vertical pixels.
// LDS qx halo tile: 18 rows x 34 cols, pixel stride 48 B (12 u32) -> bank-spread b128.
#define LSTRIDE 12  // u32 per pixel slot (32B data + 16B pad)
__global__ __launch_bounds__(256) void adder_conv(const uint4* __restrict__ qxp4,
                                                  const uint32_t* __restrict__ qwp,
                                                  float* __restrict__ out) {
    __shared__ __align__(16) uint32_t sx[18 * 34 * LSTRIDE];  // 29376 B
    __shared__ __align__(16) uint32_t swl[2304];              // 9216 B
    int tid = threadIdx.x;
    int b = blockIdx.x;
    int n = b >> 5;
    int rem = b & 31;
    int h0 = (rem >> 2) * 16, w0 = (rem & 3) * 32;

    for (int q = tid; q < 2304; q += 256) swl[q] = qwp[q];

    for (int q = tid; q < 612; q += 256) {  // 18*34 halo pixels
        int r = q / 34, cc = q % 34;
        int gh = h0 - 1 + r, gw = w0 - 1 + cc;
        uint4 a, bb;
        if ((unsigned)gh < 128u && (unsigned)gw < 128u) {
            const uint4* src = qxp4 + (size_t)(n * 16384 + gh * 128 + gw) * 2;
            a = src[0]; bb = src[1];
        } else {
            a = make_uint4(0x80808080u, 0x80808080u, 0x80808080u, 0x80808080u);
            bb = a;  // quantized zero (bias 128)
        }
        uint4* dst = (uint4*)(sx + q * LSTRIDE);
        dst[0] = a; dst[1] = bb;
    }
    __syncthreads();

    int c  = tid & 31;   // col in tile
    int rr = tid >> 5;   // row-pair 0..7 -> out rows rr*2, rr*2+1

    // register neighborhood: halo rows rr*2..rr*2+3, halo cols c..c+2
    uint4 qx[4][3][2];
    #pragma unroll
    for (int dr = 0; dr < 4; ++dr)
        #pragma unroll
        for (int dc = 0; dc < 3; ++dc) {
            const uint4* p = (const uint4*)(sx + ((rr * 2 + dr) * 34 + (c + dc)) * LSTRIDE);
            qx[dr][dc][0] = p[0];
            qx[dr][dc][1] = p[1];
        }

    size_t obase = ((size_t)(n * 32) * 128 + (h0 + rr * 2)) * 128 + (w0 + c);
    #pragma unroll 1
    for (int f = 0; f < 32; ++f) {
        uint32_t a0x = 0, a0y = 0, a1x = 0, a1y = 0;  // 4 independent sad chains
        #pragma unroll
        for (int kh = 0; kh < 3; ++kh)
            #pragma unroll
            for (int kw = 0; kw < 3; ++kw) {
                const uint4* wp = (const uint4*)(swl + ((f * 9 + kh * 3 + kw) * 8));
                uint4 wv0 = wp[0], wv1 = wp[1];
                uint4 x0 = qx[kh][kw][0],     x1 = qx[kh][kw][1];
                uint4 y0 = qx[kh + 1][kw][0], y1 = qx[kh + 1][kw][1];
                a0x = sadu8(x0.x, wv0.x, a0x); a0y = sadu8(x0.y, wv0.y, a0y);
                a0x = sadu8(x0.z, wv0.z, a0x); a0y = sadu8(x0.w, wv0.w, a0y);
                a0x = sadu8(x1.x, wv1.x, a0x); a0y = sadu8(x1.y, wv1.y, a0y);
                a0x = sadu8(x1.z, wv1.z, a0x); a0y = sadu8(x1.w, wv1.w, a0y);
                a1x = sadu8(y0.x, wv0.x, a1x); a1y = sadu8(y0.y, wv0.y, a1y);
                a1x = sadu8(y0.z, wv0.z, a1x); a1y = sadu8(y0.w, wv0.w, a1y);
                a1x = sadu8(y1.x, wv1.x, a1x); a1y = sadu8(y1.y, wv1.y, a1y);
                a1x = sadu8(y1.z, wv1.z, a1x); a1y = sadu8(y1.w, wv1.w, a1y);
            }
        out[obase + (size_t)f * 16384]       = -(float)(a0x + a0y) * INPUT_SCALE;
        out[obase + (size_t)f * 16384 + 128] = -(float)(a1x + a1y) * INPUT_SCALE;
    }
}

extern "C" void kernel_launch(void* const* d_in, const int* in_sizes, int n_in,
                              void* d_out, int out_size, void* d_ws, size_t ws_size,
                              hipStream_t stream) {
    const float* x = (const float*)d_in[0];       // (16,32,128,128)
    const float* w = (const float*)d_in[1];       // (32,32,3,3)
    float* out = (float*)d_out;                   // (16,32,128,128)

    uint32_t* qwp = (uint32_t*)d_ws;                          // 9216 B
    uint4* qxp4 = (uint4*)((char*)d_ws + 16384);              // 8,388,608 B

    quant_weight<<<1, 256, 0, stream>>>(w, qwp);
    quant_pack_x<<<256, 256, 0, stream>>>((const float4*)x, qxp4);
    adder_conv<<<512, 256, 0, stream>>>(qxp4, qwp, out);
}

// Round 2
// 51.979 us; speedup vs baseline: 1.0277x; 1.0277x over previous
//
#include <hip/hip_runtime.h>
#include <stdint.h>

#define INPUT_SCALE 0.0078125f   // 2^-7

__device__ __forceinline__ uint32_t sadu8(uint32_t a, uint32_t b, uint32_t c) {
#if __has_builtin(__builtin_amdgcn_sad_u8)
    return __builtin_amdgcn_sad_u8(a, b, c);
#else
    uint32_t d;
    asm("v_sad_u8 %0, %1, %2, %3" : "=v"(d) : "v"(a), "v"(b), "v"(c));
    return d;
#endif
}

__device__ __forceinline__ uint32_t qbyte(float x) {
    // round(clip(x*128, -127, 127)) + 128  (rintf = round-half-even, matches jnp.round)
    float v = fminf(fmaxf(x * 128.0f, -127.0f), 127.0f);
    return (uint32_t)((int)rintf(v) + 128);
}

// ---------------- Kernel A: weight scale + quantize + pack ----------------
// qwp layout: u = (f*9 + kpos)*8 + cg ; byte b of u32 = channel 4*cg+b, kpos = kh*3+kw
__global__ __launch_bounds__(1024) void quant_weight(const float* __restrict__ w,
                                                     uint32_t* __restrict__ qwp) {
    __shared__ float red[1024];
    __shared__ float s_inv;
    int tid = threadIdx.x;
    float m = 0.0f;
    for (int i = tid; i < 9216; i += 1024) m = fmaxf(m, fabsf(w[i]));
    red[tid] = m;
    __syncthreads();
    for (int s = 512; s > 0; s >>= 1) {
        if (tid < s) red[tid] = fmaxf(red[tid], red[tid + s]);
        __syncthreads();
    }
    if (tid == 0) {
        float s = fmaxf(red[0] / 127.0f, 1e-8f);
        int e; float fr = frexpf(s, &e);            // s = fr * 2^e, fr in [0.5,1)
        int k = (fr >= 0.70710678118654752f) ? e : e - 1;  // round(log2(s))
        s_inv = exp2f((float)(-k));                 // 1/s_w, exact power of 2
    }
    __syncthreads();
    float inv = s_inv;
    for (int u = tid; u < 2304; u += 1024) {
        int f = u / 72, rem = u % 72, kpos = rem / 8, cg = rem % 8;
        int kh = kpos / 3, kw = kpos % 3;
        uint32_t pk = 0;
        #pragma unroll
        for (int b = 0; b < 4; ++b) {
            int c = cg * 4 + b;
            float v = w[((f * 32 + c) * 3 + kh) * 3 + kw] * inv;
            v = fminf(fmaxf(v, -127.0f), 127.0f);
            pk |= ((uint32_t)((int)rintf(v) + 128) & 0xFFu) << (8 * b);
        }
        qwp[u] = pk;
    }
}

// ---------------- Kernel B: fused quantize + SAD conv ----------------
// Block: 32 (w) x 16 (h) tile of one image. 256 threads: lane owns 2 vertical pixels.
// LDS qx halo tile: 18 rows x 34 cols, pixel stride 48 B (12 u32) -> bank-spread b128.
// Weights read from qwp with block-uniform indices -> scalar loads (s_load), no DS/VALU cost.
#define LSTRIDE 12  // u32 per pixel slot (32B data + 16B pad)
__global__ __launch_bounds__(256) void adder_conv_fused(const float* __restrict__ x,
                                                        const uint32_t* __restrict__ qwp,
                                                        float* __restrict__ out) {
    __shared__ __align__(16) uint32_t sx[18 * 34 * LSTRIDE];  // 29376 B
    int tid = threadIdx.x;
    int b = blockIdx.x;
    int n = b >> 5;
    int rem = b & 31;
    int h0 = (rem >> 2) * 16, w0 = (rem & 3) * 32;

    // quantize + pack the 18x34 halo (32 channels -> 8 u32 per pixel) into LDS
    for (int q = tid; q < 4896; q += 256) {  // 612 pixels * 8 channel-groups
        int pixel = q >> 3, cg = q & 7;
        int r = pixel / 34, cc = pixel - r * 34;
        int gh = h0 - 1 + r, gw = w0 - 1 + cc;
        uint32_t pk = 0x80808080u;           // quantized zero padding (bias 128)
        if ((unsigned)gh < 128u && (unsigned)gw < 128u) {
            const float* base = x + (((size_t)n * 32 + cg * 4) * 128 + gh) * 128 + gw;
            pk = qbyte(base[0])
               | (qbyte(base[16384]) << 8)
               | (qbyte(base[32768]) << 16)
               | (qbyte(base[49152]) << 24);
        }
        sx[pixel * LSTRIDE + cg] = pk;
    }
    __syncthreads();

    int c  = tid & 31;   // col in tile
    int rr = tid >> 5;   // row-pair 0..7 -> out rows rr*2, rr*2+1

    // register neighborhood: halo rows rr*2..rr*2+3, halo cols c..c+2
    uint4 qx[4][3][2];
    #pragma unroll
    for (int dr = 0; dr < 4; ++dr)
        #pragma unroll
        for (int dc = 0; dc < 3; ++dc) {
            const uint4* p = (const uint4*)(sx + ((rr * 2 + dr) * 34 + (c + dc)) * LSTRIDE);
            qx[dr][dc][0] = p[0];
            qx[dr][dc][1] = p[1];
        }

    size_t obase = ((size_t)(n * 32) * 128 + (h0 + rr * 2)) * 128 + (w0 + c);
    #pragma unroll 1
    for (int f = 0; f < 32; ++f) {
        const uint32_t* wf = qwp + f * 72;   // block-uniform -> s_load via constant cache
        uint32_t a0x = 0, a0y = 0, a1x = 0, a1y = 0;  // 4 independent sad chains
        #pragma unroll
        for (int t = 0; t < 9; ++t) {
            int kh = t / 3, kw = t - kh * 3;
            uint4 wv0 = *(const uint4*)(wf + t * 8);
            uint4 wv1 = *(const uint4*)(wf + t * 8 + 4);
            uint4 x0 = qx[kh][kw][0],     x1 = qx[kh][kw][1];
            uint4 y0 = qx[kh + 1][kw][0], y1 = qx[kh + 1][kw][1];
            a0x = sadu8(x0.x, wv0.x, a0x); a0y = sadu8(x0.y, wv0.y, a0y);
            a0x = sadu8(x0.z, wv0.z, a0x); a0y = sadu8(x0.w, wv0.w, a0y);
            a0x = sadu8(x1.x, wv1.x, a0x); a0y = sadu8(x1.y, wv1.y, a0y);
            a0x = sadu8(x1.z, wv1.z, a0x); a0y = sadu8(x1.w, wv1.w, a0y);
            a1x = sadu8(y0.x, wv0.x, a1x); a1y = sadu8(y0.y, wv0.y, a1y);
            a1x = sadu8(y0.z, wv0.z, a1x); a1y = sadu8(y0.w, wv0.w, a1y);
            a1x = sadu8(y1.x, wv1.x, a1x); a1y = sadu8(y1.y, wv1.y, a1y);
            a1x = sadu8(y1.z, wv1.z, a1x); a1y = sadu8(y1.w, wv1.w, a1y);
        }
        out[obase + (size_t)f * 16384]       = -(float)(a0x + a0y) * INPUT_SCALE;
        out[obase + (size_t)f * 16384 + 128] = -(float)(a1x + a1y) * INPUT_SCALE;
    }
}

extern "C" void kernel_launch(void* const* d_in, const int* in_sizes, int n_in,
                              void* d_out, int out_size, void* d_ws, size_t ws_size,
                              hipStream_t stream) {
    const float* x = (const float*)d_in[0];       // (16,32,128,128)
    const float* w = (const float*)d_in[1];       // (32,32,3,3)
    float* out = (float*)d_out;                   // (16,32,128,128)

    uint32_t* qwp = (uint32_t*)d_ws;              // 9216 B

    quant_weight<<<1, 1024, 0, stream>>>(w, qwp);
    adder_conv_fused<<<512, 256, 0, stream>>>(x, qwp, out);
}

// Round 3
// 48.391 us; speedup vs baseline: 1.1039x; 1.0742x over previous
//
#include <hip/hip_runtime.h>
#include <stdint.h>

#define INPUT_SCALE 0.0078125f   // 2^-7

__device__ __forceinline__ uint32_t sadu8(uint32_t a, uint32_t b, uint32_t c) {
#if __has_builtin(__builtin_amdgcn_sad_u8)
    return __builtin_amdgcn_sad_u8(a, b, c);
#else
    uint32_t d;
    asm("v_sad_u8 %0, %1, %2, %3" : "=v"(d) : "v"(a), "v"(b), "v"(c));
    return d;
#endif
}

__device__ __forceinline__ uint32_t qbyte(float x) {
    // round(clip(x*128, -127, 127)) + 128  (rintf = round-half-even, matches jnp.round)
    float v = fminf(fmaxf(x * 128.0f, -127.0f), 127.0f);
    return (uint32_t)((int)rintf(v) + 128);
}

// ---------------- Kernel A: weight scale + quantize + pack ----------------
// qwp layout: u = (f*9 + kpos)*8 + cg ; byte b of u32 = channel 4*cg+b, kpos = kh*3+kw
__global__ __launch_bounds__(1024) void quant_weight(const float* __restrict__ w,
                                                     uint32_t* __restrict__ qwp) {
    __shared__ float red[1024];
    __shared__ float s_inv;
    int tid = threadIdx.x;
    float m = 0.0f;
    for (int i = tid; i < 9216; i += 1024) m = fmaxf(m, fabsf(w[i]));
    red[tid] = m;
    __syncthreads();
    for (int s = 512; s > 0; s >>= 1) {
        if (tid < s) red[tid] = fmaxf(red[tid], red[tid + s]);
        __syncthreads();
    }
    if (tid == 0) {
        float s = fmaxf(red[0] / 127.0f, 1e-8f);
        int e; float fr = frexpf(s, &e);            // s = fr * 2^e, fr in [0.5,1)
        int k = (fr >= 0.70710678118654752f) ? e : e - 1;  // round(log2(s))
        s_inv = exp2f((float)(-k));                 // 1/s_w, exact power of 2
    }
    __syncthreads();
    float inv = s_inv;
    for (int u = tid; u < 2304; u += 1024) {
        int f = u / 72, rem = u % 72, kpos = rem / 8, cg = rem % 8;
        int kh = kpos / 3, kw = kpos % 3;
        uint32_t pk = 0;
        #pragma unroll
        for (int b = 0; b < 4; ++b) {
            int c = cg * 4 + b;
            float v = w[((f * 32 + c) * 3 + kh) * 3 + kw] * inv;
            v = fminf(fmaxf(v, -127.0f), 127.0f);
            pk |= ((uint32_t)((int)rintf(v) + 128) & 0xFFu) << (8 * b);
        }
        qwp[u] = pk;
    }
}

// ---------------- Kernel B: fused quantize + SAD conv ----------------
// Block: 32 (w) x 16 (h) tile of one image. 512 threads: 1 pixel/thread, 8 waves.
// LDS qx halo tile: 18 rows x 34 cols, pixel stride 48 B (12 u32) -> bank-spread.
// Weights: block-uniform s_load via scalar cache. f-loop unroll 2 overlaps
// next-f weight loads under current-f sads.
#define LSTRIDE 12  // u32 per pixel slot (32B data + 16B pad)
__global__ __launch_bounds__(512, 4) void adder_conv_fused(const float* __restrict__ x,
                                                           const uint32_t* __restrict__ qwp,
                                                           float* __restrict__ out) {
    __shared__ __align__(16) uint32_t sx[18 * 34 * LSTRIDE];  // 29376 B
    int tid = threadIdx.x;
    int b = blockIdx.x;
    int n = b >> 5;
    int rem = b & 31;
    int h0 = (rem >> 2) * 16, w0 = (rem & 3) * 32;

    // quantize + pack the 18x34 halo (32 ch -> 8 u32/pixel) into LDS.
    // Mapping: cg = q/612 so a wave's lanes sweep consecutive pixels of one
    // channel-group -> coalesced 4B-contiguous runs per (row, channel).
    for (int q = tid; q < 4896; q += 512) {          // 4896 = 612 px * 8 cg
        int cg = q / 612;
        int pixel = q - cg * 612;
        int r = pixel / 34, cc = pixel - r * 34;
        int gh = h0 - 1 + r, gw = w0 - 1 + cc;
        uint32_t pk = 0x80808080u;                   // quantized-zero padding
        if ((unsigned)gh < 128u && (unsigned)gw < 128u) {
            const float* base = x + (((size_t)n * 32 + cg * 4) * 128 + gh) * 128 + gw;
            pk = qbyte(base[0])
               | (qbyte(base[16384]) << 8)
               | (qbyte(base[32768]) << 16)
               | (qbyte(base[49152]) << 24);
        }
        sx[pixel * LSTRIDE + cg] = pk;
    }
    __syncthreads();

    int c = tid & 31;    // col in tile
    int r = tid >> 5;    // row in tile 0..15

    // register neighborhood: halo rows r..r+2, cols c..c+2 (one output pixel)
    uint4 qx[3][3][2];
    #pragma unroll
    for (int dr = 0; dr < 3; ++dr)
        #pragma unroll
        for (int dc = 0; dc < 3; ++dc) {
            const uint4* p = (const uint4*)(sx + ((r + dr) * 34 + (c + dc)) * LSTRIDE);
            qx[dr][dc][0] = p[0];
            qx[dr][dc][1] = p[1];
        }

    size_t obase = ((size_t)(n * 32) * 128 + (h0 + r)) * 128 + (w0 + c);
    #pragma unroll 2
    for (int f = 0; f < 32; ++f) {
        const uint32_t* wf = qwp + f * 72;   // block-uniform -> s_load
        uint32_t s0 = 0, s1 = 0, s2 = 0, s3 = 0;   // 4 independent sad chains
        #pragma unroll
        for (int t = 0; t < 9; ++t) {
            int kh = t / 3, kw = t - kh * 3;
            uint4 wv0 = *(const uint4*)(wf + t * 8);
            uint4 wv1 = *(const uint4*)(wf + t * 8 + 4);
            uint4 x0 = qx[kh][kw][0], x1 = qx[kh][kw][1];
            s0 = sadu8(x0.x, wv0.x, s0);
            s1 = sadu8(x0.y, wv0.y, s1);
            s2 = sadu8(x0.z, wv0.z, s2);
            s3 = sadu8(x0.w, wv0.w, s3);
            s0 = sadu8(x1.x, wv1.x, s0);
            s1 = sadu8(x1.y, wv1.y, s1);
            s2 = sadu8(x1.z, wv1.z, s2);
            s3 = sadu8(x1.w, wv1.w, s3);
        }
        out[obase + (size_t)f * 16384] = -(float)((s0 + s1) + (s2 + s3)) * INPUT_SCALE;
    }
}

extern "C" void kernel_launch(void* const* d_in, const int* in_sizes, int n_in,
                              void* d_out, int out_size, void* d_ws, size_t ws_size,
                              hipStream_t stream) {
    const float* x = (const float*)d_in[0];       // (16,32,128,128)
    const float* w = (const float*)d_in[1];       // (32,32,3,3)
    float* out = (float*)d_out;                   // (16,32,128,128)

    uint32_t* qwp = (uint32_t*)d_ws;              // 9216 B

    quant_weight<<<1, 1024, 0, stream>>>(w, qwp);
    adder_conv_fused<<<512, 512, 0, stream>>>(x, qwp, out);
}